// Round 3
// baseline (15.684 us; speedup 1.0000x reference)
//
#include <hip/hip_runtime.h>

// Problem constants (from reference)
#define O_NUM 256
#define IN_NUM 768
#define NS 32            // B*R = 8*4 samples
#define L0 128
#define L1 22
#define L2 4
// Padded LDS row strides (odd -> conflict-free for sample-strided access)
#define Y0S 133          // >= L1*6 = 132
#define Y1S 25           // >= L2*6 = 24

// (tanh(w)+1)/2 == sigmoid(2w) == 1/(1 + 2^(-2*log2(e)*w))
__device__ __forceinline__ float fast_sig2(float w) {
    float e = __builtin_amdgcn_exp2f(w * -2.8853900817779268f);
    return __builtin_amdgcn_rcpf(1.0f + e);
}

// 6-level binary-tree LUT mux, level-0 pair-diffs precomputed in d[32].
__device__ __forceinline__ float lut6_d(const float* __restrict__ w,
                                        const float* __restrict__ d,
                                        const float* __restrict__ b) {
    float v[32];
#pragma unroll
    for (int j = 0; j < 32; ++j)
        v[j] = fmaf(b[0], d[j], w[2 * j]);          // 32 fma (diffs hoisted)
#pragma unroll
    for (int lvl = 1; lvl < 6; ++lvl) {
        const int n = 32 >> lvl;
#pragma unroll
        for (int j = 0; j < n; ++j)
            v[j] = fmaf(b[lvl], v[2 * j + 1] - v[2 * j], v[2 * j]);
    }
    return v[0];
}

// Plain 6-level tree over a register row w[64].
__device__ __forceinline__ float lut6(const float* __restrict__ w, const float* __restrict__ b) {
    float v[32];
#pragma unroll
    for (int j = 0; j < 32; ++j)
        v[j] = fmaf(b[0], w[2 * j + 1] - w[2 * j], w[2 * j]);
#pragma unroll
    for (int lvl = 1; lvl < 6; ++lvl) {
        const int n = 32 >> lvl;
#pragma unroll
        for (int j = 0; j < n; ++j)
            v[j] = fmaf(b[lvl], v[2 * j + 1] - v[2 * j], v[2 * j]);
    }
    return v[0];
}

__device__ __forceinline__ void load_row_lds(float* __restrict__ w, const float* __restrict__ src) {
    const float4* p = (const float4*)src;   // rows are 256B-aligned
#pragma unroll
    for (int k = 0; k < 16; ++k) {
        float4 q = p[k];
        w[4 * k + 0] = q.x; w[4 * k + 1] = q.y; w[4 * k + 2] = q.z; w[4 * k + 3] = q.w;
    }
}

__global__ __launch_bounds__(512) void lut_quant_fc_kernel(
    const float* __restrict__ x,    // [NS][IN_NUM]
    const float* __restrict__ w0,   // [O_NUM][L0][64]
    const float* __restrict__ w1,   // [O_NUM][L1][64]
    const float* __restrict__ w2,   // [O_NUM][L2][64]
    const float* __restrict__ w3,   // [O_NUM][1][64]
    float* __restrict__ out)        // [NS][O_NUM]
{
    const int o = blockIdx.x;
    const int tid = threadIdx.x;

    __shared__ float wq1[L1 * 64];   // 5.5 KB
    __shared__ float wq2[L2 * 64];   // 1 KB
    __shared__ float wq3[64];
    __shared__ float y0[NS * Y0S];   // ~16.6 KB
    __shared__ float y1[NS * Y1S];   // ~3.1 KB

    // ---- Setup: transform w1/w2/w3 into LDS; zero pad slots ----
    if (tid < 352) {                                   // wq1: 352 float4
        float4 q = ((const float4*)(w1 + (size_t)o * (L1 * 64)))[tid];
        float4 r = { fast_sig2(q.x), fast_sig2(q.y), fast_sig2(q.z), fast_sig2(q.w) };
        ((float4*)wq1)[tid] = r;
    } else if (tid < 416) {                            // wq2: 64 float4
        int i = tid - 352;
        float4 q = ((const float4*)(w2 + (size_t)o * (L2 * 64)))[i];
        float4 r = { fast_sig2(q.x), fast_sig2(q.y), fast_sig2(q.z), fast_sig2(q.w) };
        ((float4*)wq2)[i] = r;
    } else if (tid < 432) {                            // wq3: 16 float4
        int i = tid - 416;
        float4 q = ((const float4*)(w3 + (size_t)o * 64))[i];
        float4 r = { fast_sig2(q.x), fast_sig2(q.y), fast_sig2(q.z), fast_sig2(q.w) };
        ((float4*)wq3)[i] = r;
    }
    if (tid < NS * 4) {                                // y0 pad cols 128..131 = 0
        int s = tid >> 2; int c = L0 + (tid & 3);
        y0[s * Y0S + c] = 0.0f;
    }
    if (tid < NS * 2) {                                // y1 pad cols 22..23 = 0
        int s = tid >> 1;
        y1[s * Y1S + L1 + (tid & 1)] = 0.0f;
    }

    // ---- Layer 0: cell-fast mapping (wave = 64 consecutive cells, one sample
    // per iteration -> x reads contiguous within the wave; w0 row per-thread,
    // no intra-wave redundancy). Weights live in VGPRs across 8 samples.
    const int l  = tid & 127;       // cell 0..127 (lane-consecutive)
    const int sg = tid >> 7;        // sample group 0..3

    float rw[64];
    {
        const float4* g = (const float4*)(w0 + ((size_t)o * L0 + l) * 64);
#pragma unroll
        for (int k = 0; k < 16; ++k) {
            float4 q = g[k];
            rw[4 * k + 0] = fast_sig2(q.x);
            rw[4 * k + 1] = fast_sig2(q.y);
            rw[4 * k + 2] = fast_sig2(q.z);
            rw[4 * k + 3] = fast_sig2(q.w);
        }
    }
    float d32[32];
#pragma unroll
    for (int j = 0; j < 32; ++j) d32[j] = rw[2 * j + 1] - rw[2 * j];

#pragma unroll 2
    for (int i = 0; i < 8; ++i) {
        const int s = sg * 8 + i;
        const float2* xb = (const float2*)(x + (size_t)s * IN_NUM + l * 6);  // 8B-aligned
        float2 b01 = xb[0], b23 = xb[1], b45 = xb[2];
        float b[6] = { b01.x, b01.y, b23.x, b23.y, b45.x, b45.y };
        y0[s * Y0S + l] = lut6_d(rw, d32, b);        // lane-consecutive write
    }
    __syncthreads();

    // ---- Layer 1: 32 x 22 = 704 tasks, sample-fast (weight rows broadcast) ----
    for (int t = tid; t < NS * L1; t += 512) {
        const int s = t & 31;
        const int c = t >> 5;
        float w[64];
        load_row_lds(w, &wq1[c * 64]);
        float b[6];
#pragma unroll
        for (int j = 0; j < 6; ++j) b[j] = y0[s * Y0S + c * 6 + j];
        y1[s * Y1S + c] = lut6(w, b);
    }
    __syncthreads();

    // ---- Layers 2+3 fused: one thread per sample ----
    if (tid < NS) {
        const int s = tid;
        float bits[24];
#pragma unroll
        for (int j = 0; j < 24; ++j) bits[j] = y1[s * Y1S + j];
        float c[6];
#pragma unroll
        for (int l2 = 0; l2 < 4; ++l2) {
            float w[64];
            load_row_lds(w, &wq2[l2 * 64]);
            c[l2] = lut6(w, &bits[l2 * 6]);
        }
        c[4] = 0.0f; c[5] = 0.0f;
        float w[64];
        load_row_lds(w, wq3);
        out[(size_t)s * O_NUM + o] = lut6(w, c);
    }
}

extern "C" void kernel_launch(void* const* d_in, const int* in_sizes, int n_in,
                              void* d_out, int out_size, void* d_ws, size_t ws_size,
                              hipStream_t stream) {
    const float* x  = (const float*)d_in[0];
    const float* w0 = (const float*)d_in[1];
    const float* w1 = (const float*)d_in[2];
    const float* w2 = (const float*)d_in[3];
    const float* w3 = (const float*)d_in[4];
    float* out = (float*)d_out;

    lut_quant_fc_kernel<<<dim3(O_NUM), dim3(512), 0, stream>>>(x, w0, w1, w2, w3, out);
}

// Round 4
// 11.988 us; speedup vs baseline: 1.3084x; 1.3084x over previous
//
#include <hip/hip_runtime.h>

// Problem constants (from reference)
#define O_NUM 256
#define IN_NUM 768
#define NS 32            // B*R = 8*4 samples
#define L0 128
#define L1 22
#define L2 4
// Padded LDS row strides (odd -> conflict-free for sample-strided access)
#define Y0S 133          // >= L1*6 = 132
#define Y1S 25           // >= L2*6 = 24
#define Y2S 7            // >= 6 (layer-3 bits)

// (tanh(w)+1)/2 == sigmoid(2w) == 1/(1 + 2^(-2*log2(e)*w))
__device__ __forceinline__ float fast_sig2(float w) {
    float e = __builtin_amdgcn_exp2f(w * -2.8853900817779268f);
    return __builtin_amdgcn_rcpf(1.0f + e);
}

// 6-level binary-tree LUT mux, level-0 pair-diffs precomputed in d[32].
__device__ __forceinline__ float lut6_d(const float* __restrict__ w,
                                        const float* __restrict__ d,
                                        const float* __restrict__ b) {
    float v[32];
#pragma unroll
    for (int j = 0; j < 32; ++j)
        v[j] = fmaf(b[0], d[j], w[2 * j]);
#pragma unroll
    for (int lvl = 1; lvl < 6; ++lvl) {
        const int n = 32 >> lvl;
#pragma unroll
        for (int j = 0; j < n; ++j)
            v[j] = fmaf(b[lvl], v[2 * j + 1] - v[2 * j], v[2 * j]);
    }
    return v[0];
}

// Plain 6-level tree over a register row w[64].
__device__ __forceinline__ float lut6(const float* __restrict__ w, const float* __restrict__ b) {
    float v[32];
#pragma unroll
    for (int j = 0; j < 32; ++j)
        v[j] = fmaf(b[0], w[2 * j + 1] - w[2 * j], w[2 * j]);
#pragma unroll
    for (int lvl = 1; lvl < 6; ++lvl) {
        const int n = 32 >> lvl;
#pragma unroll
        for (int j = 0; j < n; ++j)
            v[j] = fmaf(b[lvl], v[2 * j + 1] - v[2 * j], v[2 * j]);
    }
    return v[0];
}

__device__ __forceinline__ void load_row_lds(float* __restrict__ w, const float* __restrict__ src) {
    const float4* p = (const float4*)src;   // rows are 256B-aligned
#pragma unroll
    for (int k = 0; k < 16; ++k) {
        float4 q = p[k];
        w[4 * k + 0] = q.x; w[4 * k + 1] = q.y; w[4 * k + 2] = q.z; w[4 * k + 3] = q.w;
    }
}

__global__ __launch_bounds__(512) void lut_quant_fc_kernel(
    const float* __restrict__ x,    // [NS][IN_NUM]
    const float* __restrict__ w0,   // [O_NUM][L0][64]
    const float* __restrict__ w1,   // [O_NUM][L1][64]
    const float* __restrict__ w2,   // [O_NUM][L2][64]
    const float* __restrict__ w3,   // [O_NUM][1][64]
    float* __restrict__ out)        // [NS][O_NUM]
{
    const int o = blockIdx.x;
    const int tid = threadIdx.x;

    __shared__ float4 sw0[L0 * 16];  // 32 KB, XOR-swizzled rows of transformed w0
    __shared__ float wq1[L1 * 64];   // 5.5 KB
    __shared__ float wq2[L2 * 64];   // 1 KB
    __shared__ float wq3[64];
    __shared__ float y0[NS * Y0S];   // ~16.6 KB
    __shared__ float y1[NS * Y1S];   // ~3.1 KB
    __shared__ float y2[NS * Y2S];   // ~0.9 KB

    // ---- Stage w0: coalesced global float4 reads, sig2 once per weight,
    //      XOR-swizzled LDS store: row l, chunk k -> slot l*16 + (k ^ (l&15)).
    {
        const float4* g = (const float4*)(w0 + (size_t)o * (L0 * 64));
#pragma unroll
        for (int r = 0; r < 4; ++r) {
            int idx = r * 512 + tid;            // 0..2047 float4s, coalesced
            float4 q = g[idx];
            float4 t = { fast_sig2(q.x), fast_sig2(q.y), fast_sig2(q.z), fast_sig2(q.w) };
            int lw = idx >> 4, kw = idx & 15;
            sw0[lw * 16 + (kw ^ (lw & 15))] = t;
        }
    }

    // ---- Transform w1/w2/w3 into LDS; zero pad slots ----
    if (tid < 352) {                                   // wq1: 352 float4
        float4 q = ((const float4*)(w1 + (size_t)o * (L1 * 64)))[tid];
        float4 r = { fast_sig2(q.x), fast_sig2(q.y), fast_sig2(q.z), fast_sig2(q.w) };
        ((float4*)wq1)[tid] = r;
    } else if (tid < 416) {                            // wq2: 64 float4
        int i = tid - 352;
        float4 q = ((const float4*)(w2 + (size_t)o * (L2 * 64)))[i];
        float4 r = { fast_sig2(q.x), fast_sig2(q.y), fast_sig2(q.z), fast_sig2(q.w) };
        ((float4*)wq2)[i] = r;
    } else if (tid < 432) {                            // wq3: 16 float4
        int i = tid - 416;
        float4 q = ((const float4*)(w3 + (size_t)o * 64))[i];
        float4 r = { fast_sig2(q.x), fast_sig2(q.y), fast_sig2(q.z), fast_sig2(q.w) };
        ((float4*)wq3)[i] = r;
    }
    if (tid < NS * 4) {                                // y0 pad cols 128..131 = 0
        int s = tid >> 2; int c = L0 + (tid & 3);
        y0[s * Y0S + c] = 0.0f;
    }
    if (tid < NS * 2) {                                // y1 pad cols 22..23 = 0
        int s = tid >> 1;
        y1[s * Y1S + L1 + (tid & 1)] = 0.0f;
    }
    if (tid >= 64 && tid < 64 + NS * 2) {              // y2 pad cols 4..5 = 0
        int t = tid - 64; int s = t >> 1;
        y2[s * Y2S + L2 + (t & 1)] = 0.0f;
    }
    __syncthreads();

    // ---- Layer 0: thread -> (cell l, sample-group sg); row from LDS (swizzled) ----
    const int l  = tid & 127;
    const int sg = tid >> 7;

    float rw[64];
    {
        const int base = l * 16, sw = l & 15;
#pragma unroll
        for (int k = 0; k < 16; ++k) {
            float4 q = sw0[base + (k ^ sw)];
            rw[4 * k + 0] = q.x; rw[4 * k + 1] = q.y;
            rw[4 * k + 2] = q.z; rw[4 * k + 3] = q.w;
        }
    }
    float d32[32];
#pragma unroll
    for (int j = 0; j < 32; ++j) d32[j] = rw[2 * j + 1] - rw[2 * j];

#pragma unroll 2
    for (int i = 0; i < 8; ++i) {
        const int s = sg * 8 + i;
        const float2* xb = (const float2*)(x + (size_t)s * IN_NUM + l * 6);  // 8B-aligned
        float2 b01 = xb[0], b23 = xb[1], b45 = xb[2];
        float b[6] = { b01.x, b01.y, b23.x, b23.y, b45.x, b45.y };
        y0[s * Y0S + l] = lut6_d(rw, d32, b);
    }
    __syncthreads();

    // ---- Layer 1: 32 x 22 = 704 tasks, sample-fast (weight rows broadcast) ----
    for (int t = tid; t < NS * L1; t += 512) {
        const int s = t & 31;
        const int c = t >> 5;
        float w[64];
        load_row_lds(w, &wq1[c * 64]);
        float b[6];
#pragma unroll
        for (int j = 0; j < 6; ++j) b[j] = y0[s * Y0S + c * 6 + j];
        y1[s * Y1S + c] = lut6(w, b);
    }
    __syncthreads();

    // ---- Layer 2: 32 x 4 = 128 tasks in parallel ----
    if (tid < NS * L2) {
        const int s = tid & 31;
        const int c = tid >> 5;
        float w[64];
        load_row_lds(w, &wq2[c * 64]);
        float b[6];
#pragma unroll
        for (int j = 0; j < 6; ++j) b[j] = y1[s * Y1S + c * 6 + j];
        y2[s * Y2S + c] = lut6(w, b);
    }
    __syncthreads();

    // ---- Layer 3: one thread per sample ----
    if (tid < NS) {
        const int s = tid;
        float b[6];
#pragma unroll
        for (int j = 0; j < 6; ++j) b[j] = y2[s * Y2S + j];
        float w[64];
        load_row_lds(w, wq3);
        out[(size_t)s * O_NUM + o] = lut6(w, b);
    }
}

extern "C" void kernel_launch(void* const* d_in, const int* in_sizes, int n_in,
                              void* d_out, int out_size, void* d_ws, size_t ws_size,
                              hipStream_t stream) {
    const float* x  = (const float*)d_in[0];
    const float* w0 = (const float*)d_in[1];
    const float* w1 = (const float*)d_in[2];
    const float* w2 = (const float*)d_in[3];
    const float* w3 = (const float*)d_in[4];
    float* out = (float*)d_out;

    lut_quant_fc_kernel<<<dim3(O_NUM), dim3(512), 0, stream>>>(x, w0, w1, w2, w3, out);
}